// Round 6
// baseline (242.908 us; speedup 1.0000x reference)
//
#include <hip/hip_runtime.h>
#include <stdint.h>

// Problem constants (B=8,T=8192,C=256,E=64, top-2, cap_factor=1.25)
#define N_TOK   65536
#define S_SLOTS 131072
#define NEXP    64
#define CDIM    256
#define CAP     2560          // int(1.25 * 131072 / 64)
#define NCHUNK  1024          // 128 slots per chunk (= one gating block)

typedef unsigned short u16;
typedef float    fvec4  __attribute__((ext_vector_type(4)));
typedef float    f32x4  __attribute__((ext_vector_type(4)));
typedef __bf16   bf16x8 __attribute__((ext_vector_type(8)));
typedef unsigned short u16x4 __attribute__((ext_vector_type(4)));

typedef __attribute__((address_space(1))) const void gvoid_t;
typedef __attribute__((address_space(3))) void       svoid_t;

__device__ __forceinline__ u16 f2bf(float f) {          // RNE float->bf16
  uint32_t u = __builtin_bit_cast(uint32_t, f);
  u += 0x7fffu + ((u >> 16) & 1u);
  return (u16)(u >> 16);
}
__device__ __forceinline__ float bf2f(u16 h) {
  return __builtin_bit_cast(float, (uint32_t)h << 16);
}
__device__ __forceinline__ void gload16(const void* g, void* l) {
  __builtin_amdgcn_global_load_lds(
      reinterpret_cast<gvoid_t*>(reinterpret_cast<uintptr_t>(g)),
      reinterpret_cast<svoid_t*>(reinterpret_cast<uintptr_t>(l)),
      16, 0, 0);
}

// ---------------------------------------------------------------------------
// Kernel 1 (fused): even blocks = gating chunk (body ROUND-0 VERBATIM,
// verified 57-59 us three times), odd blocks = W_experts transpose tile
// (body verbatim from the verified wtrans_kernel, reusing the first 16.6 KB
// of gating's smem -> LDS stays 34 KB, occupancy unchanged). Fusing removes
// one dispatch and lets wtrans' memory work co-schedule with gating's
// LDS-stall cycles.
// DO NOT add register staging to the gating body: r2 (+128 regs) and r4
// (+32 regs) both pushed VGPR to 256 -> scratch spills (WRITE_SIZE 330-440
// MB) and 3.5x slowdown. 64-VGPR LDS staging + 16-wave TLP is the optimum.
// ---------------------------------------------------------------------------
__global__ __launch_bounds__(256) void gating_wtrans_kernel(
    const float* __restrict__ x, const float* __restrict__ Wg,
    const float* __restrict__ We_g, u16* __restrict__ x_bf16,
    float* __restrict__ slot_score, int* __restrict__ slot_eid,
    float* __restrict__ load_g, int* __restrict__ chunk_hist,
    u16* __restrict__ WT)
{
  __shared__ float smem[8448];       // GEMM: W_s[4096] + A_s[64*68]
  __shared__ int   hist_s[64];       // tail aliases smem (see offsets below)

  const int blk = blockIdx.x;

  if (blk & 1) {
    // ---- wtrans tile (verbatim body; tile aliases smem, 4160 <= 8448) ----
    float* tile = smem;              // [64][65]
    const int b = blk >> 1;
    const int e = b >> 4, tt = b & 15;
    const int k0 = (tt >> 2) * 64, d0 = (tt & 3) * 64;
    const int t = threadIdx.x;
    const int j = t & 63, i0 = t >> 6;
    const float* We = We_g + (size_t)e * 65536;
#pragma unroll
    for (int p = 0; p < 16; ++p) {
      int i = p * 4 + i0;
      tile[i * 65 + j] = We[(size_t)(k0 + i) * 256 + d0 + j];   // coalesced on d
    }
    __syncthreads();
    u16* WTe = WT + (size_t)e * 65536;
#pragma unroll
    for (int p = 0; p < 16; ++p) {
      int d = p * 4 + i0;
      WTe[(size_t)(d0 + d) * 256 + k0 + j] = f2bf(tile[j * 65 + d]); // coalesced on k
    }
    return;
  }

  // ---- gating chunk (ROUND-0 VERBATIM body; chunk id = blk>>1) ----
  float* W_s   = smem;               // [k][e] 64x64
  float* A_s   = smem + 4096;        // [m][k] pitch 68
  float* L_s   = smem;               // [m][e] pitch 65  (tail phase, <=4160)
  float* PMAXs = smem + 4160;        // [w][tok] 4x64
  float* PV1   = smem + 4416;
  int*   PI1   = (int*)(smem + 4672);
  float* PV2   = smem + 4928;
  int*   PI2   = (int*)(smem + 5184);
  float* PSUM  = smem + 5440;
  float* RINVs = smem + 5696;        // [64]
  float* PLOAD = smem + 5760;        // [256]

  const int cid = blk >> 1;
  const int t  = threadIdx.x;
  const int m0 = cid * 64;
  const int ty = t >> 4, tx = t & 15;

  if (t < 64) hist_s[t] = 0;

  float acc[4][4];
#pragma unroll
  for (int j = 0; j < 4; ++j)
#pragma unroll
    for (int i = 0; i < 4; ++i) acc[j][i] = 0.f;

  for (int kt = 0; kt < 4; ++kt) {
    const int k0 = kt * 64;
#pragma unroll
    for (int p = 0; p < 4; ++p) {     // stage W tile [64k][64e]
      int idx = p * 1024 + t * 4;
      int kk = idx >> 6, e = idx & 63;
      *(fvec4*)&W_s[kk * 64 + e] = *(const fvec4*)&Wg[(size_t)(k0 + kk) * 64 + e];
    }
#pragma unroll
    for (int p = 0; p < 4; ++p) {     // stage A tile [64m][64k] + write x_bf16
      int idx = p * 1024 + t * 4;
      int m = idx >> 6, k = idx & 63;
      fvec4 v = *(const fvec4*)&x[(size_t)(m0 + m) * 256 + k0 + k];
      *(fvec4*)&A_s[m * 68 + k] = v;
      u16x4 h;
      h.x = f2bf(v.x); h.y = f2bf(v.y); h.z = f2bf(v.z); h.w = f2bf(v.w);
      *(u16x4*)&x_bf16[(size_t)(m0 + m) * 256 + k0 + k] = h;
    }
    __syncthreads();
#pragma unroll
    for (int k4 = 0; k4 < 16; ++k4) {
      fvec4 av[4], bv[4];
#pragma unroll
      for (int j = 0; j < 4; ++j)
        av[j] = *(const fvec4*)&A_s[(ty * 4 + j) * 68 + k4 * 4];
#pragma unroll
      for (int kk = 0; kk < 4; ++kk)
        bv[kk] = *(const fvec4*)&W_s[(k4 * 4 + kk) * 64 + tx * 4];
#pragma unroll
      for (int j = 0; j < 4; ++j)
#pragma unroll
        for (int i = 0; i < 4; ++i) {
          acc[j][i] = fmaf(av[j][0], bv[0][i], acc[j][i]);
          acc[j][i] = fmaf(av[j][1], bv[1][i], acc[j][i]);
          acc[j][i] = fmaf(av[j][2], bv[2][i], acc[j][i]);
          acc[j][i] = fmaf(av[j][3], bv[3][i], acc[j][i]);
        }
    }
    __syncthreads();                  // also guards L_s alias overwrite below
  }

  // logits -> LDS (pitch 65: column access is bank-conflict-free)
#pragma unroll
  for (int j = 0; j < 4; ++j)
#pragma unroll
    for (int i = 0; i < 4; ++i)
      L_s[(ty * 4 + j) * 65 + tx * 4 + i] = acc[j][i];
  __syncthreads();

  const int w = t >> 6, lane = t & 63;

  // pass1: per-wave partial max + top-2 (on logits; softmax is monotone).
  // Ascending expert order + strict '>' == lowest-index-on-tie (lax.top_k).
  float pm = -3.4e38f, a1 = -3.4e38f, a2 = -3.4e38f;
  int   j1 = 0, j2 = 0;
#pragma unroll
  for (int ii = 0; ii < 16; ++ii) {
    int e = w * 16 + ii;
    float lg = L_s[lane * 65 + e];
    pm = fmaxf(pm, lg);
    if (lg > a1)      { a2 = a1; j2 = j1; a1 = lg; j1 = e; }
    else if (lg > a2) { a2 = lg; j2 = e; }
  }
  PMAXs[w * 64 + lane] = pm;
  PV1[w * 64 + lane] = a1; PI1[w * 64 + lane] = j1;
  PV2[w * 64 + lane] = a2; PI2[w * 64 + lane] = j2;
  __syncthreads();

  // merge the 4 sorted pairs (redundantly in every wave; each needs the max).
  // Current pair always holds LOWER expert indices than the incoming range,
  // so strict '>' on the incoming keeps lowest-index on ties.
  float m  = PMAXs[lane];
  float v1 = PV1[lane]; int i1 = PI1[lane];
  float v2 = PV2[lane]; int i2 = PI2[lane];
#pragma unroll
  for (int ww = 1; ww < 4; ++ww) {
    m = fmaxf(m, PMAXs[ww * 64 + lane]);
    float b1 = PV1[ww * 64 + lane]; int bi1 = PI1[ww * 64 + lane];
    float b2 = PV2[ww * 64 + lane]; int bi2 = PI2[ww * 64 + lane];
    if (b1 > v1) {
      if (v1 >= b2) { v2 = v1; i2 = i1; } else { v2 = b2; i2 = bi2; }
      v1 = b1; i1 = bi1;
    } else if (b1 > v2) { v2 = b1; i2 = bi1; }
  }

  // pass2: E = exp(lg - max) in place (per-wave disjoint columns) + row partial
  float s = 0.f;
#pragma unroll
  for (int ii = 0; ii < 16; ++ii) {
    int e = w * 16 + ii;
    float E = __expf(L_s[lane * 65 + e] - m);
    L_s[lane * 65 + e] = E;
    s += E;
  }
  PSUM[w * 64 + lane] = s;
  __syncthreads();

  if (w == 0) {                       // finalize: scores, ids, chunk histogram
    float rs = PSUM[lane] + PSUM[64 + lane] + PSUM[128 + lane] + PSUM[192 + lane];
    float ri = 1.0f / rs;
    RINVs[lane] = ri;
    float sc1 = L_s[lane * 65 + i1] * ri;
    float sc2 = L_s[lane * 65 + i2] * ri;
    int tg = m0 + lane;
    slot_eid[2 * tg]     = i1;
    slot_eid[2 * tg + 1] = i2;
    slot_score[2 * tg]     = sc1;
    slot_score[2 * tg + 1] = sc2;
    atomicAdd(&hist_s[i1], 1);
    atomicAdd(&hist_s[i2], 1);
  }
  __syncthreads();

  // load partials: thread t covers expert=lane, tokens [w*16, w*16+16)
  {
    float sl = 0.f;
#pragma unroll
    for (int jj = 0; jj < 16; ++jj) {
      int j = w * 16 + jj;
      sl = fmaf(L_s[j * 65 + lane], RINVs[j], sl);
    }
    PLOAD[t] = sl;
  }
  __syncthreads();
  if (t < 64) {
    float sl = PLOAD[t] + PLOAD[64 + t] + PLOAD[128 + t] + PLOAD[192 + t];
    atomicAdd(&load_g[t], sl);
    chunk_hist[cid * 64 + t] = hist_s[t];
  }
}

// ---------------------------------------------------------------------------
// Kernel 3a: per-expert exclusive scan over the 1024 chunk histograms.
// Also writes the per-expert TOTAL count (for gemm tile skipping + clamp).
// ---------------------------------------------------------------------------
__global__ __launch_bounds__(256) void scan_kernel(int* __restrict__ hist,
                                                   int* __restrict__ tot)
{
  const int e = blockIdx.x;
  const int t = threadIdx.x;
  const int lane = t & 63, w = t >> 6;
  int h[4];
#pragma unroll
  for (int i = 0; i < 4; ++i) h[i] = hist[(t * 4 + i) * 64 + e];
  int local = h[0] + h[1] + h[2] + h[3];
  int v = local;                         // inclusive wave scan
#pragma unroll
  for (int off = 1; off < 64; off <<= 1) {
    int u = __shfl_up(v, off);
    if (lane >= off) v += u;
  }
  __shared__ int wtot[4];
  if (lane == 63) wtot[w] = v;
  __syncthreads();
  int woff = 0;
  for (int i = 0; i < w; ++i) woff += wtot[i];
  int excl = woff + v - local;
  if (t == 255) tot[e] = woff + v;       // grand total for expert e
  hist[(t * 4 + 0) * 64 + e] = excl;
  hist[(t * 4 + 1) * 64 + e] = excl + h[0];
  hist[(t * 4 + 2) * 64 + e] = excl + h[0] + h[1];
  hist[(t * 4 + 3) * 64 + e] = excl + h[0] + h[1] + h[2];
}

// ---------------------------------------------------------------------------
// Kernel 3b: rank. 1024 blocks x 128 thr (one slot each). Stable FIFO rank.
// (row_token is NOT pre-zeroed anymore; gemm clamps its gather to rows
//  < tot[e], which are exactly the rows written here — FIFO ranks are
//  contiguous from 0.)
// ---------------------------------------------------------------------------
__global__ __launch_bounds__(128) void rank_kernel(
    const int* __restrict__ slot_eid, const int* __restrict__ base,
    int* __restrict__ slot2buf, int* __restrict__ row_token)
{
  const int c = blockIdx.x;
  const int t = threadIdx.x;
  const int s = c * 128 + t;
  const int lane = t & 63, w = t >> 6;
  const int e = slot_eid[s];
  __shared__ int hist0[64];
  if (t < 64) hist0[t] = 0;
  __syncthreads();
  int rank = 0, cnt = 0;
#pragma unroll
  for (int k = 0; k < 64; ++k) {
    int eo = __shfl(e, k);
    bool m = (eo == e);
    rank += (m && k < lane) ? 1 : 0;
    cnt  += m ? 1 : 0;
  }
  if (w == 0 && rank == cnt - 1) hist0[e] = cnt;   // last lane of its expert
  __syncthreads();
  int g = base[c * 64 + e] + rank + (w ? hist0[e] : 0);
  if (g < CAP) {
    slot2buf[s] = e * CAP + g;
    row_token[e * CAP + g] = s >> 1;
  } else {
    slot2buf[s] = -1;                               // capacity-dropped
  }
}

// ---------------------------------------------------------------------------
// Kernel 4: grouped expert GEMM, bf16 MFMA 16x16x32, 128x128 tile.
// BK=64 + both-sides XOR swizzle + tile-skip (verified rounds 3/5).
// v7 adds: (a) XCD-chunked blockIdx swizzle (T1; 2560%8==0 -> bijective):
// each XCD owns 8 consecutive experts, so B-panels become L2-resident per
// XCD instead of being fetched by all 8. (b) tok gather clamped to
// rows < tot[e] -> row_token needs no memset (one fewer graph node).
// ---------------------------------------------------------------------------
__global__ __launch_bounds__(256) void gemm_kernel(
    const u16* __restrict__ x_bf16, const u16* __restrict__ WT,
    const int* __restrict__ row_token, const int* __restrict__ tot,
    u16* __restrict__ y)
{
  __shared__ u16 A_s[128 * 64];      // [row][64k], row = 128B
  __shared__ u16 B_s[128 * 64];
  __shared__ int tok_s[128];

  const int bl = blockIdx.x;
  const int b = (bl & 7) * 320 + (bl >> 3);   // XCD-chunked swizzle
  const int e = b / 40;
  const int r = b % 40;
  const int m0 = (r >> 1) * 128, n0 = (r & 1) * 128;
  const int t = threadIdx.x;

  const int te = tot[e];
  if (m0 >= te) return;              // tile entirely in unread padding rows

  if (t < 128)
    tok_s[t] = (m0 + t < te) ? row_token[e * CAP + m0 + t] : 0;
  __syncthreads();

  const int w = t >> 6, lane = t & 63;
  const int rsub8 = lane >> 3;       // row within 8-row group
  const int c8    = lane & 7;        // 16B chunk within 128B row
  const int csw   = (c8 ^ rsub8) * 8;  // swizzled source chunk (u16 units)

  const u16* WTe = WT + (size_t)e * 65536;

  const int wm = w & 1, wn = w >> 1;
  const int lr = lane & 15, q = lane >> 4;

  f32x4 acc[4][4];
#pragma unroll
  for (int mt = 0; mt < 4; ++mt)
#pragma unroll
    for (int nt = 0; nt < 4; ++nt) acc[mt][nt] = (f32x4){0.f, 0.f, 0.f, 0.f};

  for (int kt = 0; kt < 4; ++kt) {
    const int k0 = kt * 64;          // u16 units
#pragma unroll
    for (int i = 0; i < 4; ++i) {
      int ra = w * 32 + i * 8 + rsub8;
      gload16(x_bf16 + (size_t)tok_s[ra] * 256 + k0 + csw,
              (char*)A_s + (size_t)(w * 32 + i * 8) * 128);
      gload16(WTe + (size_t)(n0 + ra) * 256 + k0 + csw,
              (char*)B_s + (size_t)(w * 32 + i * 8) * 128);
    }
    __syncthreads();
#pragma unroll
    for (int kk = 0; kk < 2; ++kk) {
      bf16x8 af[4], bg[4];
#pragma unroll
      for (int mt = 0; mt < 4; ++mt) {
        int row = wm * 64 + mt * 16 + lr;
        af[mt] = *(const bf16x8*)&A_s[row * 64 + (((kk * 4 + q) ^ (lr & 7)) * 8)];
      }
#pragma unroll
      for (int nt = 0; nt < 4; ++nt) {
        int row = wn * 64 + nt * 16 + lr;
        bg[nt] = *(const bf16x8*)&B_s[row * 64 + (((kk * 4 + q) ^ (lr & 7)) * 8)];
      }
#pragma unroll
      for (int mt = 0; mt < 4; ++mt)
#pragma unroll
        for (int nt = 0; nt < 4; ++nt)
          acc[mt][nt] = __builtin_amdgcn_mfma_f32_16x16x32_bf16(
              af[mt], bg[nt], acc[mt][nt], 0, 0, 0);
    }
    __syncthreads();
  }

  // C/D layout: col=lane&15, row=quad*4+reg  [verified m89/m91]
  u16* ye = y + (size_t)e * CAP * 256;
#pragma unroll
  for (int mt = 0; mt < 4; ++mt) {
    int grow = m0 + wm * 64 + mt * 16 + q * 4;
#pragma unroll
    for (int nt = 0; nt < 4; ++nt) {
      int gcol = n0 + wn * 64 + nt * 16 + lr;
#pragma unroll
      for (int rr = 0; rr < 4; ++rr)
        ye[(size_t)(grow + rr) * 256 + gcol] = f2bf(acc[mt][nt][rr]);
    }
  }
}

// ---------------------------------------------------------------------------
// Kernel 5 (fused): combine + aux loss. out[t] = s0*y[p0] + s1*y[p1]
// (dropped -> 0), wave per token. Block 0 additionally computes
// aux = mean((load/N - 1/E)^2) on its first wave (load_g complete since
// the gating dispatch).
// ---------------------------------------------------------------------------
__global__ __launch_bounds__(256) void combine_kernel(
    const u16* __restrict__ y, const int* __restrict__ slot2buf,
    const float* __restrict__ slot_score, float* __restrict__ out,
    const float* __restrict__ load_g, float* __restrict__ out_aux)
{
  if (blockIdx.x == 0 && threadIdx.x < 64) {
    const int lane = threadIdx.x;
    float l = load_g[lane] * (1.0f / 65536.0f) - (1.0f / 64.0f);
    float v = l * l;
#pragma unroll
    for (int off = 1; off < 64; off <<= 1) v += __shfl_xor(v, off);
    if (lane == 0) out_aux[0] = v * (1.0f / 64.0f);
  }
  const int tok  = blockIdx.x * 4 + (threadIdx.x >> 6);
  const int lane = threadIdx.x & 63;
  const int   p0 = slot2buf[2 * tok],   p1 = slot2buf[2 * tok + 1];
  const float s0 = slot_score[2 * tok], s1 = slot_score[2 * tok + 1];
  float o0 = 0.f, o1 = 0.f, o2 = 0.f, o3 = 0.f;
  if (p0 >= 0) {
    u16x4 h = *(const u16x4*)&y[(size_t)p0 * 256 + lane * 4];
    o0 = fmaf(s0, bf2f(h.x), o0); o1 = fmaf(s0, bf2f(h.y), o1);
    o2 = fmaf(s0, bf2f(h.z), o2); o3 = fmaf(s0, bf2f(h.w), o3);
  }
  if (p1 >= 0) {
    u16x4 h = *(const u16x4*)&y[(size_t)p1 * 256 + lane * 4];
    o0 = fmaf(s1, bf2f(h.x), o0); o1 = fmaf(s1, bf2f(h.y), o1);
    o2 = fmaf(s1, bf2f(h.z), o2); o3 = fmaf(s1, bf2f(h.w), o3);
  }
  fvec4 o = {o0, o1, o2, o3};
  *(fvec4*)&out[(size_t)tok * 256 + lane * 4] = o;
}

// ---------------------------------------------------------------------------
// Workspace layout (bytes):
//   0        slot_score f32[131072]   (512K)
//   524288   slot_eid   i32[131072]   (512K)
//   1048576  slot2buf   i32[131072]   (512K)
//   1572864  row_token  i32[163840]   (640K)  -- NOT zeroed (gemm clamps)
//   2228224  load_g     f32[64]               -- memset 0 each call
//   2359296  chunk_hist i32[1024*64]  (256K)  -- fully written by gating
//   2621440  tot        i32[64]               -- written by scan
//   4194304  x_bf16     u16[16777216] (32M)
//   37748736 WT         u16[4194304]  (8M)
//   46137344 y          u16[41943040] (80M)
// total ~124 MB
// Graph: 6 nodes (was 9): memset, gating+wtrans, scan, rank, gemm,
// combine+aux.
// ---------------------------------------------------------------------------
extern "C" void kernel_launch(void* const* d_in, const int* in_sizes, int n_in,
                              void* d_out, int out_size, void* d_ws, size_t ws_size,
                              hipStream_t stream)
{
  const float* x  = (const float*)d_in[0];
  const float* Wg = (const float*)d_in[1];
  const float* We = (const float*)d_in[2];
  float* out = (float*)d_out;

  char* ws = (char*)d_ws;
  float* slot_score = (float*)(ws + 0);
  int*   slot_eid   = (int*)(ws + 524288);
  int*   slot2buf   = (int*)(ws + 1048576);
  int*   row_token  = (int*)(ws + 1572864);
  float* load_g     = (float*)(ws + 2228224);
  int*   chunk_hist = (int*)(ws + 2359296);
  int*   tot        = (int*)(ws + 2621440);
  u16*   x_bf16     = (u16*)(ws + 4194304);
  u16*   WT         = (u16*)(ws + 37748736);
  u16*   y          = (u16*)(ws + 46137344);

  hipMemsetAsync(load_g, 0, 256, stream);

  gating_wtrans_kernel<<<2048, 256, 0, stream>>>(x, Wg, We, x_bf16, slot_score,
                                                 slot_eid, load_g, chunk_hist, WT);
  scan_kernel<<<64, 256, 0, stream>>>(chunk_hist, tot);
  rank_kernel<<<1024, 128, 0, stream>>>(slot_eid, chunk_hist, slot2buf, row_token);
  gemm_kernel<<<2560, 256, 0, stream>>>(x_bf16, WT, row_token, tot, y);
  combine_kernel<<<16384, 256, 0, stream>>>(y, slot2buf, slot_score, out,
                                            load_g, out + 16777216);
}

// Round 7
// 218.333 us; speedup vs baseline: 1.1126x; 1.1126x over previous
//
#include <hip/hip_runtime.h>
#include <stdint.h>

// Problem constants (B=8,T=8192,C=256,E=64, top-2, cap_factor=1.25)
#define N_TOK   65536
#define S_SLOTS 131072
#define NEXP    64
#define CDIM    256
#define CAP     2560          // int(1.25 * 131072 / 64)
#define NCHUNK  1024          // 128 slots per chunk (= one gating block)

typedef unsigned short u16;
typedef float    fvec4  __attribute__((ext_vector_type(4)));
typedef float    f32x4  __attribute__((ext_vector_type(4)));
typedef __bf16   bf16x8 __attribute__((ext_vector_type(8)));
typedef unsigned short u16x4 __attribute__((ext_vector_type(4)));

typedef __attribute__((address_space(1))) const void gvoid_t;
typedef __attribute__((address_space(3))) void       svoid_t;

__device__ __forceinline__ u16 f2bf(float f) {          // RNE float->bf16
  uint32_t u = __builtin_bit_cast(uint32_t, f);
  u += 0x7fffu + ((u >> 16) & 1u);
  return (u16)(u >> 16);
}
__device__ __forceinline__ float bf2f(u16 h) {
  return __builtin_bit_cast(float, (uint32_t)h << 16);
}
__device__ __forceinline__ void gload16(const void* g, void* l) {
  __builtin_amdgcn_global_load_lds(
      reinterpret_cast<gvoid_t*>(reinterpret_cast<uintptr_t>(g)),
      reinterpret_cast<svoid_t*>(reinterpret_cast<uintptr_t>(l)),
      16, 0, 0);
}

// ---------------------------------------------------------------------------
// Kernel 1: gating. fp32 GEMM (64 tok x 64 exp, K=256) + softmax + top2 +
// x->bf16 conversion + load partials + per-chunk expert histogram.
// ROUND-0 VERBATIM, STANDALONE (verified 57-59 us four times).
// Hard-won constraints, do not violate:
//  - NO register staging (r2/r4: VGPR 256 -> scratch spills, 3.5x slower).
//  - NO block-interleaved fusion with other work (r6: wtrans blocks stole
//    CU slots from this latency-bound body, 58 -> 81 us).
// ---------------------------------------------------------------------------
__global__ __launch_bounds__(256) void gating_kernel(
    const float* __restrict__ x, const float* __restrict__ Wg,
    u16* __restrict__ x_bf16, float* __restrict__ slot_score,
    int* __restrict__ slot_eid, float* __restrict__ load_g,
    int* __restrict__ chunk_hist)
{
  __shared__ float smem[8448];       // GEMM: W_s[4096] + A_s[64*68]
  __shared__ int   hist_s[64];       // tail aliases smem (see offsets below)
  float* W_s   = smem;               // [k][e] 64x64
  float* A_s   = smem + 4096;        // [m][k] pitch 68
  float* L_s   = smem;               // [m][e] pitch 65  (tail phase, <=4160)
  float* PMAXs = smem + 4160;        // [w][tok] 4x64
  float* PV1   = smem + 4416;
  int*   PI1   = (int*)(smem + 4672);
  float* PV2   = smem + 4928;
  int*   PI2   = (int*)(smem + 5184);
  float* PSUM  = smem + 5440;
  float* RINVs = smem + 5696;        // [64]
  float* PLOAD = smem + 5760;        // [256]

  const int t  = threadIdx.x;
  const int m0 = blockIdx.x * 64;
  const int ty = t >> 4, tx = t & 15;

  if (t < 64) hist_s[t] = 0;

  float acc[4][4];
#pragma unroll
  for (int j = 0; j < 4; ++j)
#pragma unroll
    for (int i = 0; i < 4; ++i) acc[j][i] = 0.f;

  for (int kt = 0; kt < 4; ++kt) {
    const int k0 = kt * 64;
#pragma unroll
    for (int p = 0; p < 4; ++p) {     // stage W tile [64k][64e]
      int idx = p * 1024 + t * 4;
      int kk = idx >> 6, e = idx & 63;
      *(fvec4*)&W_s[kk * 64 + e] = *(const fvec4*)&Wg[(size_t)(k0 + kk) * 64 + e];
    }
#pragma unroll
    for (int p = 0; p < 4; ++p) {     // stage A tile [64m][64k] + write x_bf16
      int idx = p * 1024 + t * 4;
      int m = idx >> 6, k = idx & 63;
      fvec4 v = *(const fvec4*)&x[(size_t)(m0 + m) * 256 + k0 + k];
      *(fvec4*)&A_s[m * 68 + k] = v;
      u16x4 h;
      h.x = f2bf(v.x); h.y = f2bf(v.y); h.z = f2bf(v.z); h.w = f2bf(v.w);
      *(u16x4*)&x_bf16[(size_t)(m0 + m) * 256 + k0 + k] = h;
    }
    __syncthreads();
#pragma unroll
    for (int k4 = 0; k4 < 16; ++k4) {
      fvec4 av[4], bv[4];
#pragma unroll
      for (int j = 0; j < 4; ++j)
        av[j] = *(const fvec4*)&A_s[(ty * 4 + j) * 68 + k4 * 4];
#pragma unroll
      for (int kk = 0; kk < 4; ++kk)
        bv[kk] = *(const fvec4*)&W_s[(k4 * 4 + kk) * 64 + tx * 4];
#pragma unroll
      for (int j = 0; j < 4; ++j)
#pragma unroll
        for (int i = 0; i < 4; ++i) {
          acc[j][i] = fmaf(av[j][0], bv[0][i], acc[j][i]);
          acc[j][i] = fmaf(av[j][1], bv[1][i], acc[j][i]);
          acc[j][i] = fmaf(av[j][2], bv[2][i], acc[j][i]);
          acc[j][i] = fmaf(av[j][3], bv[3][i], acc[j][i]);
        }
    }
    __syncthreads();                  // also guards L_s alias overwrite below
  }

  // logits -> LDS (pitch 65: column access is bank-conflict-free)
#pragma unroll
  for (int j = 0; j < 4; ++j)
#pragma unroll
    for (int i = 0; i < 4; ++i)
      L_s[(ty * 4 + j) * 65 + tx * 4 + i] = acc[j][i];
  __syncthreads();

  const int w = t >> 6, lane = t & 63;

  // pass1: per-wave partial max + top-2 (on logits; softmax is monotone).
  // Ascending expert order + strict '>' == lowest-index-on-tie (lax.top_k).
  float pm = -3.4e38f, a1 = -3.4e38f, a2 = -3.4e38f;
  int   j1 = 0, j2 = 0;
#pragma unroll
  for (int ii = 0; ii < 16; ++ii) {
    int e = w * 16 + ii;
    float lg = L_s[lane * 65 + e];
    pm = fmaxf(pm, lg);
    if (lg > a1)      { a2 = a1; j2 = j1; a1 = lg; j1 = e; }
    else if (lg > a2) { a2 = lg; j2 = e; }
  }
  PMAXs[w * 64 + lane] = pm;
  PV1[w * 64 + lane] = a1; PI1[w * 64 + lane] = j1;
  PV2[w * 64 + lane] = a2; PI2[w * 64 + lane] = j2;
  __syncthreads();

  // merge the 4 sorted pairs (redundantly in every wave; each needs the max).
  // Current pair always holds LOWER expert indices than the incoming range,
  // so strict '>' on the incoming keeps lowest-index on ties.
  float m  = PMAXs[lane];
  float v1 = PV1[lane]; int i1 = PI1[lane];
  float v2 = PV2[lane]; int i2 = PI2[lane];
#pragma unroll
  for (int ww = 1; ww < 4; ++ww) {
    m = fmaxf(m, PMAXs[ww * 64 + lane]);
    float b1 = PV1[ww * 64 + lane]; int bi1 = PI1[ww * 64 + lane];
    float b2 = PV2[ww * 64 + lane]; int bi2 = PI2[ww * 64 + lane];
    if (b1 > v1) {
      if (v1 >= b2) { v2 = v1; i2 = i1; } else { v2 = b2; i2 = bi2; }
      v1 = b1; i1 = bi1;
    } else if (b1 > v2) { v2 = b1; i2 = bi1; }
  }

  // pass2: E = exp(lg - max) in place (per-wave disjoint columns) + row partial
  float s = 0.f;
#pragma unroll
  for (int ii = 0; ii < 16; ++ii) {
    int e = w * 16 + ii;
    float E = __expf(L_s[lane * 65 + e] - m);
    L_s[lane * 65 + e] = E;
    s += E;
  }
  PSUM[w * 64 + lane] = s;
  __syncthreads();

  if (w == 0) {                       // finalize: scores, ids, chunk histogram
    float rs = PSUM[lane] + PSUM[64 + lane] + PSUM[128 + lane] + PSUM[192 + lane];
    float ri = 1.0f / rs;
    RINVs[lane] = ri;
    float sc1 = L_s[lane * 65 + i1] * ri;
    float sc2 = L_s[lane * 65 + i2] * ri;
    int tg = m0 + lane;
    slot_eid[2 * tg]     = i1;
    slot_eid[2 * tg + 1] = i2;
    slot_score[2 * tg]     = sc1;
    slot_score[2 * tg + 1] = sc2;
    atomicAdd(&hist_s[i1], 1);
    atomicAdd(&hist_s[i2], 1);
  }
  __syncthreads();

  // load partials: thread t covers expert=lane, tokens [w*16, w*16+16)
  {
    float sl = 0.f;
#pragma unroll
    for (int jj = 0; jj < 16; ++jj) {
      int j = w * 16 + jj;
      sl = fmaf(L_s[j * 65 + lane], RINVs[j], sl);
    }
    PLOAD[t] = sl;
  }
  __syncthreads();
  if (t < 64) {
    float sl = PLOAD[t] + PLOAD[64 + t] + PLOAD[128 + t] + PLOAD[192 + t];
    atomicAdd(&load_g[t], sl);
    chunk_hist[blockIdx.x * 64 + t] = hist_s[t];
  }
}

// ---------------------------------------------------------------------------
// Kernel 2: W_experts [e][k][d] fp32 -> WT [e][d][k] bf16 (K-fast for MFMA B).
// Standalone again (r6 proved in-gating fusion costs +23 us on gating).
// ---------------------------------------------------------------------------
__global__ __launch_bounds__(256) void wtrans_kernel(
    const float* __restrict__ W, u16* __restrict__ WT)
{
  __shared__ float tile[64 * 65];
  const int b = blockIdx.x;
  const int e = b >> 4, tt = b & 15;
  const int k0 = (tt >> 2) * 64, d0 = (tt & 3) * 64;
  const int t = threadIdx.x;
  const int j = t & 63, i0 = t >> 6;
  const float* We = W + (size_t)e * 65536;
#pragma unroll
  for (int p = 0; p < 16; ++p) {
    int i = p * 4 + i0;
    tile[i * 65 + j] = We[(size_t)(k0 + i) * 256 + d0 + j];   // coalesced on d
  }
  __syncthreads();
  u16* WTe = WT + (size_t)e * 65536;
#pragma unroll
  for (int p = 0; p < 16; ++p) {
    int d = p * 4 + i0;
    WTe[(size_t)(d0 + d) * 256 + k0 + j] = f2bf(tile[j * 65 + d]); // coalesced on k
  }
}

// ---------------------------------------------------------------------------
// Kernel 3a: per-expert exclusive scan over the 1024 chunk histograms.
// Also writes the per-expert TOTAL count (for gemm tile skipping + clamp).
// ---------------------------------------------------------------------------
__global__ __launch_bounds__(256) void scan_kernel(int* __restrict__ hist,
                                                   int* __restrict__ tot)
{
  const int e = blockIdx.x;
  const int t = threadIdx.x;
  const int lane = t & 63, w = t >> 6;
  int h[4];
#pragma unroll
  for (int i = 0; i < 4; ++i) h[i] = hist[(t * 4 + i) * 64 + e];
  int local = h[0] + h[1] + h[2] + h[3];
  int v = local;                         // inclusive wave scan
#pragma unroll
  for (int off = 1; off < 64; off <<= 1) {
    int u = __shfl_up(v, off);
    if (lane >= off) v += u;
  }
  __shared__ int wtot[4];
  if (lane == 63) wtot[w] = v;
  __syncthreads();
  int woff = 0;
  for (int i = 0; i < w; ++i) woff += wtot[i];
  int excl = woff + v - local;
  if (t == 255) tot[e] = woff + v;       // grand total for expert e
  hist[(t * 4 + 0) * 64 + e] = excl;
  hist[(t * 4 + 1) * 64 + e] = excl + h[0];
  hist[(t * 4 + 2) * 64 + e] = excl + h[0] + h[1];
  hist[(t * 4 + 3) * 64 + e] = excl + h[0] + h[1] + h[2];
}

// ---------------------------------------------------------------------------
// Kernel 3b: rank. 1024 blocks x 128 thr (one slot each). Stable FIFO rank.
// (row_token is NOT pre-zeroed; gemm clamps its gather to rows < tot[e],
//  which are exactly the rows written here — FIFO ranks contiguous from 0.)
// ---------------------------------------------------------------------------
__global__ __launch_bounds__(128) void rank_kernel(
    const int* __restrict__ slot_eid, const int* __restrict__ base,
    int* __restrict__ slot2buf, int* __restrict__ row_token)
{
  const int c = blockIdx.x;
  const int t = threadIdx.x;
  const int s = c * 128 + t;
  const int lane = t & 63, w = t >> 6;
  const int e = slot_eid[s];
  __shared__ int hist0[64];
  if (t < 64) hist0[t] = 0;
  __syncthreads();
  int rank = 0, cnt = 0;
#pragma unroll
  for (int k = 0; k < 64; ++k) {
    int eo = __shfl(e, k);
    bool m = (eo == e);
    rank += (m && k < lane) ? 1 : 0;
    cnt  += m ? 1 : 0;
  }
  if (w == 0 && rank == cnt - 1) hist0[e] = cnt;   // last lane of its expert
  __syncthreads();
  int g = base[c * 64 + e] + rank + (w ? hist0[e] : 0);
  if (g < CAP) {
    slot2buf[s] = e * CAP + g;
    row_token[e * CAP + g] = s >> 1;
  } else {
    slot2buf[s] = -1;                               // capacity-dropped
  }
}

// ---------------------------------------------------------------------------
// Kernel 4: grouped expert GEMM, bf16 MFMA 16x16x32, 128x128 tile.
// BK=64 + both-sides XOR swizzle + tile-skip (verified r3/r5) + XCD-chunked
// blockIdx swizzle + tok clamp (kept from r6 — the bundle arithmetic showed
// these were a net win even as the fusion regressed).
// ---------------------------------------------------------------------------
__global__ __launch_bounds__(256) void gemm_kernel(
    const u16* __restrict__ x_bf16, const u16* __restrict__ WT,
    const int* __restrict__ row_token, const int* __restrict__ tot,
    u16* __restrict__ y)
{
  __shared__ u16 A_s[128 * 64];      // [row][64k], row = 128B
  __shared__ u16 B_s[128 * 64];
  __shared__ int tok_s[128];

  const int bl = blockIdx.x;
  const int b = (bl & 7) * 320 + (bl >> 3);   // XCD-chunked swizzle (bijective)
  const int e = b / 40;
  const int r = b % 40;
  const int m0 = (r >> 1) * 128, n0 = (r & 1) * 128;
  const int t = threadIdx.x;

  const int te = tot[e];
  if (m0 >= te) return;              // tile entirely in unread padding rows

  if (t < 128)
    tok_s[t] = (m0 + t < te) ? row_token[e * CAP + m0 + t] : 0;
  __syncthreads();

  const int w = t >> 6, lane = t & 63;
  const int rsub8 = lane >> 3;       // row within 8-row group
  const int c8    = lane & 7;        // 16B chunk within 128B row
  const int csw   = (c8 ^ rsub8) * 8;  // swizzled source chunk (u16 units)

  const u16* WTe = WT + (size_t)e * 65536;

  const int wm = w & 1, wn = w >> 1;
  const int lr = lane & 15, q = lane >> 4;

  f32x4 acc[4][4];
#pragma unroll
  for (int mt = 0; mt < 4; ++mt)
#pragma unroll
    for (int nt = 0; nt < 4; ++nt) acc[mt][nt] = (f32x4){0.f, 0.f, 0.f, 0.f};

  for (int kt = 0; kt < 4; ++kt) {
    const int k0 = kt * 64;          // u16 units
#pragma unroll
    for (int i = 0; i < 4; ++i) {
      int ra = w * 32 + i * 8 + rsub8;
      gload16(x_bf16 + (size_t)tok_s[ra] * 256 + k0 + csw,
              (char*)A_s + (size_t)(w * 32 + i * 8) * 128);
      gload16(WTe + (size_t)(n0 + ra) * 256 + k0 + csw,
              (char*)B_s + (size_t)(w * 32 + i * 8) * 128);
    }
    __syncthreads();
#pragma unroll
    for (int kk = 0; kk < 2; ++kk) {
      bf16x8 af[4], bg[4];
#pragma unroll
      for (int mt = 0; mt < 4; ++mt) {
        int row = wm * 64 + mt * 16 + lr;
        af[mt] = *(const bf16x8*)&A_s[row * 64 + (((kk * 4 + q) ^ (lr & 7)) * 8)];
      }
#pragma unroll
      for (int nt = 0; nt < 4; ++nt) {
        int row = wn * 64 + nt * 16 + lr;
        bg[nt] = *(const bf16x8*)&B_s[row * 64 + (((kk * 4 + q) ^ (lr & 7)) * 8)];
      }
#pragma unroll
      for (int mt = 0; mt < 4; ++mt)
#pragma unroll
        for (int nt = 0; nt < 4; ++nt)
          acc[mt][nt] = __builtin_amdgcn_mfma_f32_16x16x32_bf16(
              af[mt], bg[nt], acc[mt][nt], 0, 0, 0);
    }
    __syncthreads();
  }

  // C/D layout: col=lane&15, row=quad*4+reg  [verified m89/m91]
  u16* ye = y + (size_t)e * CAP * 256;
#pragma unroll
  for (int mt = 0; mt < 4; ++mt) {
    int grow = m0 + wm * 64 + mt * 16 + q * 4;
#pragma unroll
    for (int nt = 0; nt < 4; ++nt) {
      int gcol = n0 + wn * 64 + nt * 16 + lr;
#pragma unroll
      for (int rr = 0; rr < 4; ++rr)
        ye[(size_t)(grow + rr) * 256 + gcol] = f2bf(acc[mt][nt][rr]);
    }
  }
}

// ---------------------------------------------------------------------------
// Kernel 5 (fused): combine + aux loss. out[t] = s0*y[p0] + s1*y[p1]
// (dropped -> 0), wave per token. Block 0's first wave computes
// aux = mean((load/N - 1/E)^2)  (load_g complete since gating).
// ---------------------------------------------------------------------------
__global__ __launch_bounds__(256) void combine_kernel(
    const u16* __restrict__ y, const int* __restrict__ slot2buf,
    const float* __restrict__ slot_score, float* __restrict__ out,
    const float* __restrict__ load_g, float* __restrict__ out_aux)
{
  if (blockIdx.x == 0 && threadIdx.x < 64) {
    const int lane = threadIdx.x;
    float l = load_g[lane] * (1.0f / 65536.0f) - (1.0f / 64.0f);
    float v = l * l;
#pragma unroll
    for (int off = 1; off < 64; off <<= 1) v += __shfl_xor(v, off);
    if (lane == 0) out_aux[0] = v * (1.0f / 64.0f);
  }
  const int tok  = blockIdx.x * 4 + (threadIdx.x >> 6);
  const int lane = threadIdx.x & 63;
  const int   p0 = slot2buf[2 * tok],   p1 = slot2buf[2 * tok + 1];
  const float s0 = slot_score[2 * tok], s1 = slot_score[2 * tok + 1];
  float o0 = 0.f, o1 = 0.f, o2 = 0.f, o3 = 0.f;
  if (p0 >= 0) {
    u16x4 h = *(const u16x4*)&y[(size_t)p0 * 256 + lane * 4];
    o0 = fmaf(s0, bf2f(h.x), o0); o1 = fmaf(s0, bf2f(h.y), o1);
    o2 = fmaf(s0, bf2f(h.z), o2); o3 = fmaf(s0, bf2f(h.w), o3);
  }
  if (p1 >= 0) {
    u16x4 h = *(const u16x4*)&y[(size_t)p1 * 256 + lane * 4];
    o0 = fmaf(s1, bf2f(h.x), o0); o1 = fmaf(s1, bf2f(h.y), o1);
    o2 = fmaf(s1, bf2f(h.z), o2); o3 = fmaf(s1, bf2f(h.w), o3);
  }
  fvec4 o = {o0, o1, o2, o3};
  *(fvec4*)&out[(size_t)tok * 256 + lane * 4] = o;
}

// ---------------------------------------------------------------------------
// Workspace layout (bytes):
//   0        slot_score f32[131072]   (512K)
//   524288   slot_eid   i32[131072]   (512K)
//   1048576  slot2buf   i32[131072]   (512K)
//   1572864  row_token  i32[163840]   (640K)  -- NOT zeroed (gemm clamps)
//   2228224  load_g     f32[64]               -- memset 0 each call
//   2359296  chunk_hist i32[1024*64]  (256K)  -- fully written by gating
//   2621440  tot        i32[64]               -- written by scan
//   4194304  x_bf16     u16[16777216] (32M)
//   37748736 WT         u16[4194304]  (8M)
//   46137344 y          u16[41943040] (80M)
// total ~124 MB
// Graph: 7 nodes: memset, gating, wtrans, scan, rank, gemm, combine+aux.
// ---------------------------------------------------------------------------
extern "C" void kernel_launch(void* const* d_in, const int* in_sizes, int n_in,
                              void* d_out, int out_size, void* d_ws, size_t ws_size,
                              hipStream_t stream)
{
  const float* x  = (const float*)d_in[0];
  const float* Wg = (const float*)d_in[1];
  const float* We = (const float*)d_in[2];
  float* out = (float*)d_out;

  char* ws = (char*)d_ws;
  float* slot_score = (float*)(ws + 0);
  int*   slot_eid   = (int*)(ws + 524288);
  int*   slot2buf   = (int*)(ws + 1048576);
  int*   row_token  = (int*)(ws + 1572864);
  float* load_g     = (float*)(ws + 2228224);
  int*   chunk_hist = (int*)(ws + 2359296);
  int*   tot        = (int*)(ws + 2621440);
  u16*   x_bf16     = (u16*)(ws + 4194304);
  u16*   WT         = (u16*)(ws + 37748736);
  u16*   y          = (u16*)(ws + 46137344);

  hipMemsetAsync(load_g, 0, 256, stream);

  gating_kernel<<<1024, 256, 0, stream>>>(x, Wg, x_bf16, slot_score, slot_eid,
                                          load_g, chunk_hist);
  wtrans_kernel<<<1024, 256, 0, stream>>>(We, WT);
  scan_kernel<<<64, 256, 0, stream>>>(chunk_hist, tot);
  rank_kernel<<<1024, 128, 0, stream>>>(slot_eid, chunk_hist, slot2buf, row_token);
  gemm_kernel<<<2560, 256, 0, stream>>>(x_bf16, WT, row_token, tot, y);
  combine_kernel<<<16384, 256, 0, stream>>>(y, slot2buf, slot_score, out,
                                            load_g, out + 16777216);
}